// Round 1
// baseline (115.744 us; speedup 1.0000x reference)
//
#include <hip/hip_runtime.h>

// QConv2d: out[b] = U @ rho[b] @ U^T where U = kron(uc[:,2:4], kron(ux,uy)) (cols 128..255 of full u)
// Factored: W_{c1,c2} = K @ rho_blk @ K^T (64x64), out = A-combine of the 4 W blocks.
// One block per batch (256 blocks = 1/CU), 256 threads, 64 KiB LDS.

#define TPB 256

__global__ __launch_bounds__(TPB, 1) void qconv_fused(
    const float* __restrict__ rho,   // [256][128][128]
    const float* __restrict__ ux,    // [8][8]
    const float* __restrict__ uy,    // [8][8]
    const float* __restrict__ uc,    // [4][4]
    float* __restrict__ out)         // [256][256][256]
{
    __shared__ alignas(16) float sKT[4096];      // KT[a][pp] = K[pp][a]
    __shared__ alignas(16) float sRho[2][4096];  // double-buffered 64x64 rho block [a][r]
    __shared__ alignas(16) float sTt[4096];      // Tt[r][pp] = (K @ rho_blk)^T

    const int tid = threadIdx.x;
    const int b   = blockIdx.x;

    // Build K^T in LDS: K[pp][a] = ux[pp/8][a/8] * uy[pp%8][a%8]
    for (int t = tid; t < 4096; t += TPB) {
        int a = t >> 6, pp = t & 63;
        sKT[t] = ux[((pp >> 3) << 3) + (a >> 3)] * uy[((pp & 7) << 3) + (a & 7)];
    }

    // A[c][c1] = uc[c][c1+2]
    float A0[4], A1[4];
#pragma unroll
    for (int c = 0; c < 4; ++c) {
        A0[c] = uc[(c << 2) + 2];
        A1[c] = uc[(c << 2) + 3];
    }

    const int tx = tid & 15;        // 16 col-groups of 4
    const int ty = tid >> 4;        // 16 row-groups of 4
    const int i0 = ty << 2;
    const int j0 = tx << 2;

    const float* rb_base = rho + (size_t)b * 16384;

    // preload (c1,c2)=(0,0) block: rows a (0..63), cols r (0..63)
    for (int t = tid; t < 1024; t += TPB) {
        int a = t >> 4, r4 = (t & 15) << 2;
        *(float4*)&sRho[0][(a << 6) + r4] = *(const float4*)&rb_base[a * 128 + r4];
    }

    float W[4][4][4];  // [cc=c1*2+c2][di][dj], stays in VGPRs (cc loop fully unrolled)

#pragma unroll
    for (int cc = 0; cc < 4; ++cc) {
        const int buf = cc & 1;
        __syncthreads();  // sRho[buf] visible; sTt free (prev stage2 done)

        // prefetch next rho block into registers (latency hidden behind both k-loops)
        float4 pf[4];
        if (cc < 3) {
            const int c1n = (cc + 1) >> 1, c2n = (cc + 1) & 1;
            const float* rb = rb_base + c1n * (64 * 128) + c2n * 64;
#pragma unroll
            for (int p = 0; p < 4; ++p) {
                int t = tid + p * TPB;
                int a = t >> 4, r4 = (t & 15) << 2;
                pf[p] = *(const float4*)&rb[a * 128 + r4];
            }
        }

        // stage 1: Tt[r][pp] = sum_a rho_blk[a][r] * K[pp][a]
        float acc[4][4];
#pragma unroll
        for (int di = 0; di < 4; ++di)
#pragma unroll
            for (int dj = 0; dj < 4; ++dj) acc[di][dj] = 0.f;

#pragma unroll 4
        for (int k = 0; k < 64; ++k) {
            float4 q1 = *(const float4*)&sRho[buf][(k << 6) + i0];
            float4 q2 = *(const float4*)&sKT[(k << 6) + j0];
            float v1[4] = {q1.x, q1.y, q1.z, q1.w};
            float v2[4] = {q2.x, q2.y, q2.z, q2.w};
#pragma unroll
            for (int di = 0; di < 4; ++di)
#pragma unroll
                for (int dj = 0; dj < 4; ++dj)
                    acc[di][dj] += v1[di] * v2[dj];
        }

#pragma unroll
        for (int di = 0; di < 4; ++di) {
            float4 v = make_float4(acc[di][0], acc[di][1], acc[di][2], acc[di][3]);
            *(float4*)&sTt[((i0 + di) << 6) + j0] = v;
        }
        __syncthreads();  // sTt ready

        // stage 2: W[pp][ps] = sum_rr Tt[rr][pp] * K[ps][rr]
#pragma unroll
        for (int di = 0; di < 4; ++di)
#pragma unroll
            for (int dj = 0; dj < 4; ++dj) W[cc][di][dj] = 0.f;

#pragma unroll 4
        for (int k = 0; k < 64; ++k) {
            float4 q1 = *(const float4*)&sTt[(k << 6) + i0];
            float4 q2 = *(const float4*)&sKT[(k << 6) + j0];
            float v1[4] = {q1.x, q1.y, q1.z, q1.w};
            float v2[4] = {q2.x, q2.y, q2.z, q2.w};
#pragma unroll
            for (int di = 0; di < 4; ++di)
#pragma unroll
                for (int dj = 0; dj < 4; ++dj)
                    W[cc][di][dj] += v1[di] * v2[dj];
        }

        // store prefetched block (all sRho[buf^1] readers finished before mid-iter sync)
        if (cc < 3) {
#pragma unroll
            for (int p = 0; p < 4; ++p) {
                int t = tid + p * TPB;
                int a = t >> 4, r4 = (t & 15) << 2;
                *(float4*)&sRho[buf ^ 1][(a << 6) + r4] = pf[p];
            }
        }
    }

    // epilogue: out[b, c*64+pp, cs*64+ps] = sum_{c1,c2} A[c][c1]*A[cs][c2]*W[c1*2+c2][pp][ps]
    float* ob = out + (size_t)b * 65536;
#pragma unroll
    for (int c = 0; c < 4; ++c) {
#pragma unroll
        for (int cs = 0; cs < 4; ++cs) {
            const float k00 = A0[c] * A0[cs];
            const float k01 = A0[c] * A1[cs];
            const float k10 = A1[c] * A0[cs];
            const float k11 = A1[c] * A1[cs];
#pragma unroll
            for (int di = 0; di < 4; ++di) {
                float4 v;
                v.x = k00 * W[0][di][0] + k01 * W[1][di][0] + k10 * W[2][di][0] + k11 * W[3][di][0];
                v.y = k00 * W[0][di][1] + k01 * W[1][di][1] + k10 * W[2][di][1] + k11 * W[3][di][1];
                v.z = k00 * W[0][di][2] + k01 * W[1][di][2] + k10 * W[2][di][2] + k11 * W[3][di][2];
                v.w = k00 * W[0][di][3] + k01 * W[1][di][3] + k10 * W[2][di][3] + k11 * W[3][di][3];
                *(float4*)&ob[(size_t)((c << 6) + i0 + di) * 256 + (cs << 6) + j0] = v;
            }
        }
    }
}

extern "C" void kernel_launch(void* const* d_in, const int* in_sizes, int n_in,
                              void* d_out, int out_size, void* d_ws, size_t ws_size,
                              hipStream_t stream) {
    const float* rho = (const float*)d_in[0];
    const float* ux  = (const float*)d_in[1];
    const float* uy  = (const float*)d_in[2];
    const float* uc  = (const float*)d_in[3];
    float* out = (float*)d_out;
    qconv_fused<<<dim3(256), dim3(TPB), 0, stream>>>(rho, ux, uy, uc, out);
}

// Round 2
// 91.013 us; speedup vs baseline: 1.2717x; 1.2717x over previous
//
#include <hip/hip_runtime.h>

// QConv2d factored: out[(c,px'py'),(cs,qx'qy')] = sum_{c1,c2} uc[c][c1+2] uc[cs][c2+2] *
//   (contract px,py with ux,uy on left; qx,qy with ux,uy on right of rho block (c1,c2)).
// Thread = (c1,c2 = wave, px,qx = lane). In-register 8x8 fiber over (py,qy); one padded
// intra-wave LDS transpose swaps to (px,qx); 8x8 coefs are wave-uniform (s_load -> SGPR fma).
// 2 blocks/batch (grid 512, 2 blocks/CU, 8 waves/CU); block pair (i,i+8) -> same XCD for L2 reuse.

#define TPB 256

__global__ __launch_bounds__(TPB, 2) void qconv_fused(
    const float* __restrict__ rho,   // [256][128][128]
    const float* __restrict__ ux,    // [8][8]
    const float* __restrict__ uy,    // [8][8]
    const float* __restrict__ uc,    // [4][4]
    float* __restrict__ out)         // [256][256][256]
{
    __shared__ alignas(16) float L[4][64][68];  // 69632 B: per-wave transpose / W-exchange

    const int tid  = threadIdx.x;
    const int w    = tid >> 6;          // wave id: c1 = w>>1, c2 = w&1
    const int lane = tid & 63;
    const int c1   = w >> 1, c2 = w & 1;
    const int px   = lane >> 3, qx = lane & 7;

    const int blk = blockIdx.x;
    const int b   = ((blk >> 4) << 3) | (blk & 7);  // batch
    const int h   = (blk >> 3) & 1;                  // output half: c in {2h, 2h+1}

    const float* rb = rho + (size_t)b * 16384 + (size_t)((c1 << 6) + (px << 3)) * 128
                      + (c2 << 6) + (qx << 3);

    float X[64], Y[64];

    // ---- load X[py][qy] = rho_blk[(px,py),(qx,qy)] : 16 x b128
#pragma unroll
    for (int py = 0; py < 8; ++py) {
        float4 lo = *(const float4*)(rb + py * 128);
        float4 hi = *(const float4*)(rb + py * 128 + 4);
        X[py * 8 + 0] = lo.x; X[py * 8 + 1] = lo.y; X[py * 8 + 2] = lo.z; X[py * 8 + 3] = lo.w;
        X[py * 8 + 4] = hi.x; X[py * 8 + 5] = hi.y; X[py * 8 + 6] = hi.z; X[py * 8 + 7] = hi.w;
    }

    // ---- phase A1: contract py with uy (left):  Y[i][q] = sum_k uy[i][k] X[k][q]
#pragma unroll
    for (int i = 0; i < 8; ++i) {
#pragma unroll
        for (int q = 0; q < 8; ++q) Y[i * 8 + q] = 0.f;
#pragma unroll
        for (int k = 0; k < 8; ++k) {
            const float cf = uy[i * 8 + k];           // uniform -> SGPR
#pragma unroll
            for (int q = 0; q < 8; ++q) Y[i * 8 + q] += cf * X[k * 8 + q];
        }
    }
    // ---- phase A2: contract qy with uy (right): X[i][j] = sum_k uy[j][k] Y[i][k]
#pragma unroll
    for (int t = 0; t < 64; ++t) X[t] = 0.f;
#pragma unroll
    for (int j = 0; j < 8; ++j) {
#pragma unroll
        for (int k = 0; k < 8; ++k) {
            const float cf = uy[j * 8 + k];
#pragma unroll
            for (int i = 0; i < 8; ++i) X[i * 8 + j] += cf * Y[i * 8 + k];
        }
    }

    // ---- intra-wave transpose: (in-thread py',qy') <-> (lane px,qx)
#pragma unroll
    for (int e = 0; e < 64; ++e) L[w][e][lane] = X[e];   // lanes contiguous: conflict-free
    __syncthreads();
#pragma unroll
    for (int f4 = 0; f4 < 16; ++f4) {                    // row read, stride 68: 2-way max
        float4 v = *(const float4*)&L[w][lane][f4 * 4];
        X[f4 * 4 + 0] = v.x; X[f4 * 4 + 1] = v.y; X[f4 * 4 + 2] = v.z; X[f4 * 4 + 3] = v.w;
    }
    // now thread identity: (py',qy') = (lane>>3, lane&7); X[px][qx]

    // ---- phase B1: contract px with ux (left):  Y[i][q] = sum_k ux[i][k] X[k][q]
#pragma unroll
    for (int i = 0; i < 8; ++i) {
#pragma unroll
        for (int q = 0; q < 8; ++q) Y[i * 8 + q] = 0.f;
#pragma unroll
        for (int k = 0; k < 8; ++k) {
            const float cf = ux[i * 8 + k];
#pragma unroll
            for (int q = 0; q < 8; ++q) Y[i * 8 + q] += cf * X[k * 8 + q];
        }
    }
    // ---- phase B2: contract qx with ux (right): X[i][j] = sum_k ux[j][k] Y[i][k]
#pragma unroll
    for (int t = 0; t < 64; ++t) X[t] = 0.f;
#pragma unroll
    for (int j = 0; j < 8; ++j) {
#pragma unroll
        for (int k = 0; k < 8; ++k) {
            const float cf = ux[j * 8 + k];
#pragma unroll
            for (int i = 0; i < 8; ++i) X[i * 8 + j] += cf * Y[i * 8 + k];
        }
    }
    // X[px'][qx'] = W_{c1,c2}[(px',py'),(qx',qy')]

    __syncthreads();  // all transpose reads of L done before overwrite

    // ---- W exchange: spatial-row-major layout L[w][px'*8+py'][qx'*8+qy']
    {
        const int pyp = lane >> 3, qyp = lane & 7;
#pragma unroll
        for (int px_ = 0; px_ < 8; ++px_)
#pragma unroll
            for (int qx_ = 0; qx_ < 8; ++qx_)
                L[w][px_ * 8 + pyp][qx_ * 8 + qyp] = X[px_ * 8 + qx_];  // ~2-way: free
    }
    __syncthreads();

    // ---- epilogue: combine channels, write half the output rows (c in {2h,2h+1})
    // uniform channel coefs (s_load): rows of uc for this block's two c values
    const float b00 = uc[(2 * h) * 4 + 2],     b01 = uc[(2 * h) * 4 + 3];
    const float b10 = uc[(2 * h + 1) * 4 + 2], b11 = uc[(2 * h + 1) * 4 + 3];
    float a2[4][2];
#pragma unroll
    for (int cs = 0; cs < 4; ++cs) { a2[cs][0] = uc[cs * 4 + 2]; a2[cs][1] = uc[cs * 4 + 3]; }

    float* ob = out + (size_t)b * 65536;
#pragma unroll
    for (int i = 0; i < 4; ++i) {
        const int g  = tid + 256 * i;
        const int sp = g >> 4;          // spatial row px'*8+py'
        const int qg = g & 15;          // 4-col group
        float4 wv[4];
#pragma unroll
        for (int ww = 0; ww < 4; ++ww) wv[ww] = *(const float4*)&L[ww][sp][qg * 4];
#pragma unroll
        for (int cc = 0; cc < 2; ++cc) {
            const float e0 = cc ? b10 : b00;
            const float e1 = cc ? b11 : b01;
            const int   c  = 2 * h + cc;
#pragma unroll
            for (int cs = 0; cs < 4; ++cs) {
                const float k00 = e0 * a2[cs][0], k01 = e0 * a2[cs][1];
                const float k10 = e1 * a2[cs][0], k11 = e1 * a2[cs][1];
                float4 v;
                v.x = k00 * wv[0].x + k01 * wv[1].x + k10 * wv[2].x + k11 * wv[3].x;
                v.y = k00 * wv[0].y + k01 * wv[1].y + k10 * wv[2].y + k11 * wv[3].y;
                v.z = k00 * wv[0].z + k01 * wv[1].z + k10 * wv[2].z + k11 * wv[3].z;
                v.w = k00 * wv[0].w + k01 * wv[1].w + k10 * wv[2].w + k11 * wv[3].w;
                *(float4*)&ob[(size_t)((c * 64 + sp) * 256 + cs * 64 + qg * 4)] = v;
            }
        }
    }
}

extern "C" void kernel_launch(void* const* d_in, const int* in_sizes, int n_in,
                              void* d_out, int out_size, void* d_ws, size_t ws_size,
                              hipStream_t stream) {
    const float* rho = (const float*)d_in[0];
    const float* ux  = (const float*)d_in[1];
    const float* uy  = (const float*)d_in[2];
    const float* uc  = (const float*)d_in[3];
    float* out = (float*)d_out;
    qconv_fused<<<dim3(512), dim3(TPB), 0, stream>>>(rho, ux, uy, uc, out);
}